// Round 1
// baseline (1221.894 us; speedup 1.0000x reference)
//
#include <hip/hip_runtime.h>
#include <cstdint>
#include <cstddef>

// ---------------------------------------------------------------------------
// GCN 2-layer encoder.  Pipeline per launch:
//   1. count in-degree per node (int atomics), dis = rsqrt(deg+1)
//   2. exclusive scan -> CSR row_ptr; fill col[] + per-edge weight wgt[]
//   3. h1 = x @ W1                (fp32 register-tiled GEMM)
//   4. out1 = relu(Agg(h1) + b1)  (wave-per-node gather, staged in d_out)
//   5. h2 = out1 @ W2
//   6. d_out = Agg(h2) + b2
// Self-loops contribute dis[i]^2 * h[i] directly (not stored in CSR).
// ---------------------------------------------------------------------------

__global__ void zero_int(int* __restrict__ p, int n) {
  int i = blockIdx.x * blockDim.x + threadIdx.x;
  if (i < n) p[i] = 0;
}

__global__ void count_edges(const int* __restrict__ dst, int E, int* __restrict__ count) {
  int e = blockIdx.x * blockDim.x + threadIdx.x;
  if (e < E) atomicAdd(&count[dst[e]], 1);
}

__global__ void compute_dis(const int* __restrict__ count, float* __restrict__ dis, int N) {
  int i = blockIdx.x * blockDim.x + threadIdx.x;
  if (i < N) dis[i] = rsqrtf((float)(count[i] + 1));  // +1 = self loop; deg>0 always
}

// --- hierarchical exclusive scan over count[0..N) -> rowptr, pos -------------
__global__ void scan_partial(const int* __restrict__ count, int* __restrict__ bsum, int N) {
  __shared__ int s[256];
  int t = threadIdx.x, b = blockIdx.x;
  int base = b * 1024 + t * 4;
  int sum = 0;
#pragma unroll
  for (int i = 0; i < 4; i++) sum += (base + i < N) ? count[base + i] : 0;
  s[t] = sum;
  __syncthreads();
  for (int d = 128; d > 0; d >>= 1) {
    if (t < d) s[t] += s[t + d];
    __syncthreads();
  }
  if (t == 0) bsum[b] = s[0];
}

__global__ void scan_blocksums(int* __restrict__ bsum, int nb) {
  __shared__ int s[256];
  int t = threadIdx.x;
  int v = (t < nb) ? bsum[t] : 0;
  s[t] = v;
  __syncthreads();
  for (int d = 1; d < 256; d <<= 1) {
    int add = (t >= d) ? s[t - d] : 0;
    __syncthreads();
    s[t] += add;
    __syncthreads();
  }
  if (t < nb) bsum[t] = s[t] - v;  // exclusive
}

__global__ void scan_final(const int* __restrict__ count, const int* __restrict__ bsum,
                           int* __restrict__ rowptr, int* __restrict__ pos, int N, int E) {
  __shared__ int s[256];
  int t = threadIdx.x, b = blockIdx.x;
  int base = b * 1024 + t * 4;
  int c[4];
  int sum = 0;
#pragma unroll
  for (int i = 0; i < 4; i++) {
    c[i] = (base + i < N) ? count[base + i] : 0;
    sum += c[i];
  }
  int v = sum;
  s[t] = v;
  __syncthreads();
  for (int d = 1; d < 256; d <<= 1) {
    int add = (t >= d) ? s[t - d] : 0;
    __syncthreads();
    s[t] += add;
    __syncthreads();
  }
  int run = bsum[b] + (s[t] - v);
#pragma unroll
  for (int i = 0; i < 4; i++) {
    if (base + i < N) {
      rowptr[base + i] = run;
      pos[base + i] = run;
      run += c[i];
    }
  }
  if (b == 0 && t == 0) rowptr[N] = E;
}

__global__ void fill_edges(const int* __restrict__ src, const int* __restrict__ dst, int E,
                           const float* __restrict__ dis, int* __restrict__ pos,
                           int* __restrict__ col, float* __restrict__ wgt) {
  int e = blockIdx.x * blockDim.x + threadIdx.x;
  if (e >= E) return;
  int d = dst[e], s = src[e];
  int slot = atomicAdd(&pos[d], 1);
  col[slot] = s;
  wgt[slot] = dis[s] * dis[d];
}

// --- GEMM: C[M][64] = A[M][K] @ W[K][64] (fp32, register tiled) -------------
__device__ __forceinline__ float4 ld4(const float* p) { return *(const float4*)p; }

template <int K>
__global__ void gemm64(const float* __restrict__ A, const float* __restrict__ W,
                       float* __restrict__ C, int M) {
  const int c0 = (threadIdx.x & 15) << 2;  // 16 col-quads cover 64 cols
  const int rq = threadIdx.x >> 4;         // 16 row-quads per block
  const int r0 = blockIdx.x * 64 + rq * 4;
  if (r0 >= M) return;
  float4 acc[4];
#pragma unroll
  for (int i = 0; i < 4; i++) acc[i] = make_float4(0.f, 0.f, 0.f, 0.f);
  size_t aoff[4];
  bool ok[4];
#pragma unroll
  for (int i = 0; i < 4; i++) {
    int r = r0 + i;
    ok[i] = (r < M);
    aoff[i] = (size_t)(ok[i] ? r : (M - 1)) * K;  // clamp: no OOB, result discarded
  }
  for (int k = 0; k < K; k += 4) {
    float4 w0 = ld4(W + (size_t)(k + 0) * 64 + c0);
    float4 w1 = ld4(W + (size_t)(k + 1) * 64 + c0);
    float4 w2 = ld4(W + (size_t)(k + 2) * 64 + c0);
    float4 w3 = ld4(W + (size_t)(k + 3) * 64 + c0);
#pragma unroll
    for (int i = 0; i < 4; i++) {
      float4 xv = ld4(A + aoff[i] + k);
      acc[i].x += xv.x * w0.x + xv.y * w1.x + xv.z * w2.x + xv.w * w3.x;
      acc[i].y += xv.x * w0.y + xv.y * w1.y + xv.z * w2.y + xv.w * w3.y;
      acc[i].z += xv.x * w0.z + xv.y * w1.z + xv.z * w2.z + xv.w * w3.z;
      acc[i].w += xv.x * w0.w + xv.y * w1.w + xv.z * w2.w + xv.w * w3.w;
    }
  }
#pragma unroll
  for (int i = 0; i < 4; i++)
    if (ok[i]) *(float4*)&C[(size_t)(r0 + i) * 64 + c0] = acc[i];
}

// --- aggregation: wave per node, lane = feature -----------------------------
__device__ __forceinline__ int rl_i(int v, int l) { return __builtin_amdgcn_readlane(v, l); }
__device__ __forceinline__ float rl_f(float v, int l) {
  return __uint_as_float((unsigned)__builtin_amdgcn_readlane((int)__float_as_uint(v), l));
}

__global__ void agg_kernel(const float* __restrict__ h, const int* __restrict__ rowptr,
                           const int* __restrict__ col, const float* __restrict__ wgt,
                           const float* __restrict__ dis, const float* __restrict__ bias,
                           float* __restrict__ out, int N, int relu) {
  int wid = (blockIdx.x * blockDim.x + threadIdx.x) >> 6;
  int lane = threadIdx.x & 63;
  if (wid >= N) return;
  int start = rowptr[wid], end = rowptr[wid + 1];
  float di = dis[wid];
  float a0 = di * di * h[(size_t)wid * 64 + lane];  // self-loop term
  float a1 = 0.f, a2 = 0.f, a3 = 0.f;
  for (int base = start; base < end; base += 64) {
    int e = base + lane;
    int sj = 0;
    float wj = 0.f;
    if (e < end) {
      sj = col[e];
      wj = wgt[e];
    }
    int cnt = min(64, end - base);
    int j = 0;
    // 4-way unroll: 4 independent gathers in flight per wave (readlane = VALU,
    // avoids ds_bpermute LDS-pipe traffic that __shfl would emit)
    for (; j + 3 < cnt; j += 4) {
      int s0 = rl_i(sj, j), s1 = rl_i(sj, j + 1), s2 = rl_i(sj, j + 2), s3 = rl_i(sj, j + 3);
      float w0 = rl_f(wj, j), w1 = rl_f(wj, j + 1), w2 = rl_f(wj, j + 2), w3 = rl_f(wj, j + 3);
      float g0 = h[(size_t)s0 * 64 + lane];
      float g1 = h[(size_t)s1 * 64 + lane];
      float g2 = h[(size_t)s2 * 64 + lane];
      float g3 = h[(size_t)s3 * 64 + lane];
      a0 += w0 * g0;
      a1 += w1 * g1;
      a2 += w2 * g2;
      a3 += w3 * g3;
    }
    for (; j < cnt; j++) {
      int s0 = rl_i(sj, j);
      float w0 = rl_f(wj, j);
      a0 += w0 * h[(size_t)s0 * 64 + lane];
    }
  }
  float acc = (a0 + a1) + (a2 + a3) + bias[lane];
  if (relu) acc = fmaxf(acc, 0.f);
  out[(size_t)wid * 64 + lane] = acc;
}

// ---------------------------------------------------------------------------
extern "C" void kernel_launch(void* const* d_in, const int* in_sizes, int n_in,
                              void* d_out, int out_size, void* d_ws, size_t ws_size,
                              hipStream_t stream) {
  const float* x = (const float*)d_in[0];
  const int* ei = (const int*)d_in[1];
  const float* W1 = (const float*)d_in[2];
  const float* b1 = (const float*)d_in[3];
  const float* W2 = (const float*)d_in[4];
  const float* b2 = (const float*)d_in[5];

  const int IN = 256;
  const int E = in_sizes[1] / 2;
  const int N = in_sizes[0] / IN;
  const int* src = ei;       // edge_index[0]
  const int* dst = ei + E;   // edge_index[1]

  // workspace carve-up (256B aligned)
  char* ws = (char*)d_ws;
  size_t off = 0;
  auto alloc = [&](size_t bytes) -> void* {
    void* p = ws + off;
    off += (bytes + 255) & ~(size_t)255;
    return p;
  };
  int* count = (int*)alloc((size_t)N * 4);
  int* pos = (int*)alloc((size_t)N * 4);
  int* rowptr = (int*)alloc((size_t)(N + 1) * 4);
  float* dis = (float*)alloc((size_t)N * 4);
  int* bsum = (int*)alloc(4096);
  int* col = (int*)alloc((size_t)E * 4);
  float* wgt = (float*)alloc((size_t)E * 4);
  float* h = (float*)alloc((size_t)N * 64 * 4);  // h1, later reused as h2
  float* out1 = (float*)d_out;                   // layer-1 output staged in d_out
  float* outf = (float*)d_out;

  const int tb = 256;
  const int nb = (N + 1023) / 1024;

  zero_int<<<(N + tb - 1) / tb, tb, 0, stream>>>(count, N);
  count_edges<<<(E + tb - 1) / tb, tb, 0, stream>>>(dst, E, count);
  compute_dis<<<(N + tb - 1) / tb, tb, 0, stream>>>(count, dis, N);
  scan_partial<<<nb, 256, 0, stream>>>(count, bsum, N);
  scan_blocksums<<<1, 256, 0, stream>>>(bsum, nb);
  scan_final<<<nb, 256, 0, stream>>>(count, bsum, rowptr, pos, N, E);
  fill_edges<<<(E + tb - 1) / tb, tb, 0, stream>>>(src, dst, E, dis, pos, col, wgt);

  gemm64<256><<<(N + 63) / 64, 256, 0, stream>>>(x, W1, h, N);
  agg_kernel<<<(N + 3) / 4, 256, 0, stream>>>(h, rowptr, col, wgt, dis, b1, out1, N, 1);
  gemm64<64><<<(N + 63) / 64, 256, 0, stream>>>(out1, W2, h, N);
  agg_kernel<<<(N + 3) / 4, 256, 0, stream>>>(h, rowptr, col, wgt, dis, b2, outf, N, 0);
}

// Round 2
// 819.748 us; speedup vs baseline: 1.4906x; 1.4906x over previous
//
#include <hip/hip_runtime.h>
#include <cstdint>
#include <cstddef>

// ---------------------------------------------------------------------------
// GCN 2-layer encoder.  Pipeline per launch:
//   1. count in-degree per node (int atomics), dis = rsqrt(deg+1)
//   2. exclusive scan -> CSR row_ptr; fill col[] + per-edge weight wgt[]
//   3. h1 = x @ W1                (fp32 GEMM, W staged in LDS)
//   4. out1 = relu(Agg(h1) + b1)  (2-edges-per-wave gather, staged in d_out)
//   5. h2 = out1 @ W2
//   6. d_out = Agg(h2) + b2
// Self-loops contribute dis[i]^2 * h[i] directly (not stored in CSR).
// ---------------------------------------------------------------------------

__global__ void zero_int(int* __restrict__ p, int n) {
  int i = blockIdx.x * blockDim.x + threadIdx.x;
  if (i < n) p[i] = 0;
}

__global__ void count_edges(const int* __restrict__ dst, int E, int* __restrict__ count) {
  int e = blockIdx.x * blockDim.x + threadIdx.x;
  if (e < E) atomicAdd(&count[dst[e]], 1);
}

__global__ void compute_dis(const int* __restrict__ count, float* __restrict__ dis, int N) {
  int i = blockIdx.x * blockDim.x + threadIdx.x;
  if (i < N) dis[i] = rsqrtf((float)(count[i] + 1));  // +1 = self loop; deg>0 always
}

// --- hierarchical exclusive scan over count[0..N) -> rowptr, pos -------------
__global__ void scan_partial(const int* __restrict__ count, int* __restrict__ bsum, int N) {
  __shared__ int s[256];
  int t = threadIdx.x, b = blockIdx.x;
  int base = b * 1024 + t * 4;
  int sum = 0;
#pragma unroll
  for (int i = 0; i < 4; i++) sum += (base + i < N) ? count[base + i] : 0;
  s[t] = sum;
  __syncthreads();
  for (int d = 128; d > 0; d >>= 1) {
    if (t < d) s[t] += s[t + d];
    __syncthreads();
  }
  if (t == 0) bsum[b] = s[0];
}

__global__ void scan_blocksums(int* __restrict__ bsum, int nb) {
  __shared__ int s[256];
  int t = threadIdx.x;
  int v = (t < nb) ? bsum[t] : 0;
  s[t] = v;
  __syncthreads();
  for (int d = 1; d < 256; d <<= 1) {
    int add = (t >= d) ? s[t - d] : 0;
    __syncthreads();
    s[t] += add;
    __syncthreads();
  }
  if (t < nb) bsum[t] = s[t] - v;  // exclusive
}

__global__ void scan_final(const int* __restrict__ count, const int* __restrict__ bsum,
                           int* __restrict__ rowptr, int* __restrict__ pos, int N, int E) {
  __shared__ int s[256];
  int t = threadIdx.x, b = blockIdx.x;
  int base = b * 1024 + t * 4;
  int c[4];
  int sum = 0;
#pragma unroll
  for (int i = 0; i < 4; i++) {
    c[i] = (base + i < N) ? count[base + i] : 0;
    sum += c[i];
  }
  int v = sum;
  s[t] = v;
  __syncthreads();
  for (int d = 1; d < 256; d <<= 1) {
    int add = (t >= d) ? s[t - d] : 0;
    __syncthreads();
    s[t] += add;
    __syncthreads();
  }
  int run = bsum[b] + (s[t] - v);
#pragma unroll
  for (int i = 0; i < 4; i++) {
    if (base + i < N) {
      rowptr[base + i] = run;
      pos[base + i] = run;
      run += c[i];
    }
  }
  if (b == 0 && t == 0) rowptr[N] = E;
}

__global__ void fill_edges(const int* __restrict__ src, const int* __restrict__ dst, int E,
                           const float* __restrict__ dis, int* __restrict__ pos,
                           int* __restrict__ col, float* __restrict__ wgt) {
  int e = blockIdx.x * blockDim.x + threadIdx.x;
  if (e >= E) return;
  int d = dst[e], s = src[e];
  int slot = atomicAdd(&pos[d], 1);
  col[slot] = s;
  wgt[slot] = dis[s] * dis[d];
}

// --- GEMM: C[M][64] = A[M][K] @ W[K][64], W staged in LDS -------------------
// Block: 256 threads = 16 col-quads x 16 row-quads -> 64 rows x 64 cols.
// W (K x 64 fp32) lives entirely in LDS: K=256 -> 64 KB (static max), K=64 -> 16 KB.
// Per k-step a wave fetches only 64 B of unique A (16-lane broadcast) and does
// 64 v_fma per thread -> VALU-bound once W traffic is off the L1/L2 path.
template <int K>
__global__ __launch_bounds__(256) void gemm64(const float* __restrict__ A,
                                              const float* __restrict__ W,
                                              float* __restrict__ C, int M) {
  __shared__ float4 wlds[K * 16];  // K rows x 16 float4 (64 cols)
  {
    const float4* W4 = (const float4*)W;
    for (int i = threadIdx.x; i < K * 16; i += 256) wlds[i] = W4[i];
  }
  __syncthreads();

  const int c0 = threadIdx.x & 15;   // which float4 of the 64-col row
  const int rq = threadIdx.x >> 4;   // row quad within block
  const int r0 = blockIdx.x * 64 + rq * 4;
  if (r0 >= M) return;

  float4 acc[4];
#pragma unroll
  for (int i = 0; i < 4; i++) acc[i] = make_float4(0.f, 0.f, 0.f, 0.f);
  size_t aoff[4];
  bool ok[4];
#pragma unroll
  for (int i = 0; i < 4; i++) {
    int r = r0 + i;
    ok[i] = (r < M);
    aoff[i] = (size_t)(ok[i] ? r : (M - 1)) * K;  // clamp: no OOB, result discarded
  }

#pragma unroll 2
  for (int k = 0; k < K; k += 4) {
    float4 xv[4];
#pragma unroll
    for (int i = 0; i < 4; i++) xv[i] = *(const float4*)(A + aoff[i] + k);
    float4 w0 = wlds[(k + 0) * 16 + c0];
    float4 w1 = wlds[(k + 1) * 16 + c0];
    float4 w2 = wlds[(k + 2) * 16 + c0];
    float4 w3 = wlds[(k + 3) * 16 + c0];
#pragma unroll
    for (int i = 0; i < 4; i++) {
      acc[i].x += xv[i].x * w0.x + xv[i].y * w1.x + xv[i].z * w2.x + xv[i].w * w3.x;
      acc[i].y += xv[i].x * w0.y + xv[i].y * w1.y + xv[i].z * w2.y + xv[i].w * w3.y;
      acc[i].z += xv[i].x * w0.z + xv[i].y * w1.z + xv[i].z * w2.z + xv[i].w * w3.z;
      acc[i].w += xv[i].x * w0.w + xv[i].y * w1.w + xv[i].z * w2.w + xv[i].w * w3.w;
    }
  }
#pragma unroll
  for (int i = 0; i < 4; i++)
    if (ok[i]) *(float4*)&C[(size_t)(r0 + i) * 64 + c0 * 4] = acc[i];
}

// --- aggregation: wave per node, TWO edges per wave in flight ---------------
// Lanes 0-31 (half 0) process even edge slots, lanes 32-63 (half 1) odd slots.
// Each half gathers a full 256 B h-row as 32 x float2. 4-way unroll => 8
// independent 256 B gathers in flight per wave (vs 4 in round 1).
__global__ __launch_bounds__(256) void agg_kernel(
    const float2* __restrict__ h, const int* __restrict__ rowptr, const int* __restrict__ col,
    const float* __restrict__ wgt, const float* __restrict__ dis, const float* __restrict__ bias,
    float2* __restrict__ out, int N, int relu) {
  int wid = (blockIdx.x * blockDim.x + threadIdx.x) >> 6;
  if (wid >= N) return;
  int lane = threadIdx.x & 63;
  int sub = lane & 31;    // float2 index within the 64-float row
  int half = lane >> 5;   // which edge of the pair

  int start = rowptr[wid], end = rowptr[wid + 1];
  float di = dis[wid];

  float2 a0 = make_float2(0.f, 0.f), a1 = a0, a2 = a0, a3 = a0;
  {  // self-loop term, counted once (half 0 only; halves are summed at the end)
    float2 self = h[(size_t)wid * 32 + sub];
    if (half == 0) {
      a0.x = di * di * self.x;
      a0.y = di * di * self.y;
    }
  }

  for (int base = start; base < end; base += 64) {
    int e = base + lane;
    int sj = 0;
    float wj = 0.f;
    if (e < end) {
      sj = col[e];
      wj = wgt[e];
    }
    int cnt = end - base;
    if (cnt > 64) cnt = 64;
    int rounds = (cnt + 1) >> 1;  // edge pairs in this chunk
    int t = 0;
    for (; t + 4 <= rounds; t += 4) {
      int i0 = 2 * t + half;  // uniform within each 32-lane half -> bpermute ok
      int s0 = __shfl(sj, i0), s1 = __shfl(sj, i0 + 2), s2 = __shfl(sj, i0 + 4),
          s3 = __shfl(sj, i0 + 6);
      float w0 = __shfl(wj, i0), w1 = __shfl(wj, i0 + 2), w2 = __shfl(wj, i0 + 4),
            w3 = __shfl(wj, i0 + 6);
      float2 g0 = h[(size_t)s0 * 32 + sub];
      float2 g1 = h[(size_t)s1 * 32 + sub];
      float2 g2 = h[(size_t)s2 * 32 + sub];
      float2 g3 = h[(size_t)s3 * 32 + sub];
      a0.x += w0 * g0.x; a0.y += w0 * g0.y;
      a1.x += w1 * g1.x; a1.y += w1 * g1.y;
      a2.x += w2 * g2.x; a2.y += w2 * g2.y;
      a3.x += w3 * g3.x; a3.y += w3 * g3.y;
    }
    for (; t < rounds; t++) {
      int i0 = 2 * t + half;  // may point one past cnt for odd cnt: wj there is 0
      int s0 = __shfl(sj, i0);
      float w0 = __shfl(wj, i0);
      float2 g0 = h[(size_t)s0 * 32 + sub];
      a0.x += w0 * g0.x; a0.y += w0 * g0.y;
    }
  }

  float sx = (a0.x + a1.x) + (a2.x + a3.x);
  float sy = (a0.y + a1.y) + (a2.y + a3.y);
  sx += __shfl_down(sx, 32);  // fold half 1 into half 0 (width = wave = 64)
  sy += __shfl_down(sy, 32);
  if (half == 0) {
    float2 bv = ((const float2*)bias)[sub];
    float ox = sx + bv.x, oy = sy + bv.y;
    if (relu) {
      ox = fmaxf(ox, 0.f);
      oy = fmaxf(oy, 0.f);
    }
    out[(size_t)wid * 32 + sub] = make_float2(ox, oy);
  }
}

// ---------------------------------------------------------------------------
extern "C" void kernel_launch(void* const* d_in, const int* in_sizes, int n_in,
                              void* d_out, int out_size, void* d_ws, size_t ws_size,
                              hipStream_t stream) {
  const float* x = (const float*)d_in[0];
  const int* ei = (const int*)d_in[1];
  const float* W1 = (const float*)d_in[2];
  const float* b1 = (const float*)d_in[3];
  const float* W2 = (const float*)d_in[4];
  const float* b2 = (const float*)d_in[5];

  const int IN = 256;
  const int E = in_sizes[1] / 2;
  const int N = in_sizes[0] / IN;
  const int* src = ei;      // edge_index[0]
  const int* dst = ei + E;  // edge_index[1]

  // workspace carve-up (256B aligned)
  char* ws = (char*)d_ws;
  size_t off = 0;
  auto alloc = [&](size_t bytes) -> void* {
    void* p = ws + off;
    off += (bytes + 255) & ~(size_t)255;
    return p;
  };
  int* count = (int*)alloc((size_t)N * 4);
  int* pos = (int*)alloc((size_t)N * 4);
  int* rowptr = (int*)alloc((size_t)(N + 1) * 4);
  float* dis = (float*)alloc((size_t)N * 4);
  int* bsum = (int*)alloc(4096);
  int* col = (int*)alloc((size_t)E * 4);
  float* wgt = (float*)alloc((size_t)E * 4);
  float* h = (float*)alloc((size_t)N * 64 * 4);  // h1, later reused as h2
  float* out1 = (float*)d_out;                   // layer-1 output staged in d_out
  float* outf = (float*)d_out;

  const int tb = 256;
  const int nb = (N + 1023) / 1024;

  zero_int<<<(N + tb - 1) / tb, tb, 0, stream>>>(count, N);
  count_edges<<<(E + tb - 1) / tb, tb, 0, stream>>>(dst, E, count);
  compute_dis<<<(N + tb - 1) / tb, tb, 0, stream>>>(count, dis, N);
  scan_partial<<<nb, 256, 0, stream>>>(count, bsum, N);
  scan_blocksums<<<1, 256, 0, stream>>>(bsum, nb);
  scan_final<<<nb, 256, 0, stream>>>(count, bsum, rowptr, pos, N, E);
  fill_edges<<<(E + tb - 1) / tb, tb, 0, stream>>>(src, dst, E, dis, pos, col, wgt);

  gemm64<256><<<(N + 63) / 64, 256, 0, stream>>>(x, W1, h, N);
  agg_kernel<<<(N + 3) / 4, 256, 0, stream>>>((const float2*)h, rowptr, col, wgt, dis, b1,
                                              (float2*)out1, N, 1);
  gemm64<64><<<(N + 63) / 64, 256, 0, stream>>>(out1, W2, h, N);
  agg_kernel<<<(N + 3) / 4, 256, 0, stream>>>((const float2*)h, rowptr, col, wgt, dis, b2,
                                              (float2*)outf, N, 0);
}

// Round 3
// 643.342 us; speedup vs baseline: 1.8993x; 1.2742x over previous
//
#include <hip/hip_runtime.h>
#include <cstdint>
#include <cstddef>

// ---------------------------------------------------------------------------
// GCN 2-layer encoder.  Pipeline per launch:
//   1. bin edges by dst>>7 (128 nodes/bin) into a bin-contiguous buffer
//   2. per-bin LDS counters -> degree, dis = rsqrt(deg+1)
//   3. exclusive scan -> CSR rowptr; per-bin LDS cursors -> col[] + wgt[]
//      (all scattered writes confined to ~16 KB L2-resident windows)
//   4. h1 = x @ W1                (fp32 GEMM, W staged in LDS)
//   5. out1 = relu(Agg(h1) + b1)  (2-edges-per-wave gather, staged in d_out)
//   6. h2 = out1 @ W2 ; d_out = Agg(h2) + b2
// Self-loops contribute dis[i]^2 * h[i] directly (not stored in CSR).
// ---------------------------------------------------------------------------

#define BIN_SHIFT 7
#define BIN_NODES 128
#define MAX_BINS 1024

__global__ void zero_int(int* __restrict__ p, int n) {
  int i = blockIdx.x * blockDim.x + threadIdx.x;
  if (i < n) p[i] = 0;
}

// --- pass A: histogram of edges per bin -------------------------------------
__global__ __launch_bounds__(256) void bin_count(const int* __restrict__ dst, int E, int nbins,
                                                 int* __restrict__ binCnt) {
  __shared__ int h[MAX_BINS];
  for (int i = threadIdx.x; i < nbins; i += 256) h[i] = 0;
  __syncthreads();
  int stride = gridDim.x * 256;
  for (int e = blockIdx.x * 256 + threadIdx.x; e < E; e += stride)
    atomicAdd(&h[dst[e] >> BIN_SHIFT], 1);
  __syncthreads();
  for (int i = threadIdx.x; i < nbins; i += 256)
    if (h[i]) atomicAdd(&binCnt[i], h[i]);
}

// --- exclusive scan over <=1024 bins, single block --------------------------
__global__ __launch_bounds__(256) void bin_scan(const int* __restrict__ binCnt, int nbins, int E,
                                                int* __restrict__ binStart,
                                                int* __restrict__ binCursor) {
  __shared__ int s[256];
  int t = threadIdx.x;
  int c[4];
  int sum = 0;
#pragma unroll
  for (int i = 0; i < 4; i++) {
    int idx = t * 4 + i;
    c[i] = (idx < nbins) ? binCnt[idx] : 0;
    sum += c[i];
  }
  int v = sum;
  s[t] = v;
  __syncthreads();
  for (int d = 1; d < 256; d <<= 1) {
    int add = (t >= d) ? s[t - d] : 0;
    __syncthreads();
    s[t] += add;
    __syncthreads();
  }
  int run = s[t] - v;  // exclusive prefix
#pragma unroll
  for (int i = 0; i < 4; i++) {
    int idx = t * 4 + i;
    if (idx < nbins) {
      binStart[idx] = run;
      binCursor[idx] = run;
      run += c[i];
    }
  }
  if (t == 0) binStart[nbins] = E;
}

// --- pass B: partition (src,dst) into bin-contiguous binbuf -----------------
__global__ __launch_bounds__(256) void bin_fill(const int* __restrict__ src,
                                                const int* __restrict__ dst, int E, int nbins,
                                                int* __restrict__ binCursor,
                                                int2* __restrict__ binbuf) {
  __shared__ int h[MAX_BINS];
  __shared__ int lbase[MAX_BINS];
  __shared__ int lcnt[MAX_BINS];
  int chunk = (E + gridDim.x - 1) / gridDim.x;
  int c0 = blockIdx.x * chunk;
  int c1 = min(E, c0 + chunk);
  for (int i = threadIdx.x; i < nbins; i += 256) {
    h[i] = 0;
    lcnt[i] = 0;
  }
  __syncthreads();
  for (int e = c0 + threadIdx.x; e < c1; e += 256) atomicAdd(&h[dst[e] >> BIN_SHIFT], 1);
  __syncthreads();
  for (int i = threadIdx.x; i < nbins; i += 256)
    lbase[i] = h[i] ? atomicAdd(&binCursor[i], h[i]) : 0;
  __syncthreads();
  for (int e = c0 + threadIdx.x; e < c1; e += 256) {
    int d = dst[e];
    int b = d >> BIN_SHIFT;
    int idx = lbase[b] + atomicAdd(&lcnt[b], 1);
    binbuf[idx] = make_int2(src[e], d);
  }
}

// --- pass C: per-bin node degree + dis --------------------------------------
__global__ __launch_bounds__(256) void node_count_dis(const int2* __restrict__ binbuf,
                                                      const int* __restrict__ binStart, int N,
                                                      int* __restrict__ count,
                                                      float* __restrict__ dis) {
  __shared__ int cnt[BIN_NODES];
  int b = blockIdx.x;
  int nodeBase = b << BIN_SHIFT;
  if (threadIdx.x < BIN_NODES) cnt[threadIdx.x] = 0;
  __syncthreads();
  int s0 = binStart[b], s1 = binStart[b + 1];
  for (int i = s0 + threadIdx.x; i < s1; i += 256) atomicAdd(&cnt[binbuf[i].y - nodeBase], 1);
  __syncthreads();
  if (threadIdx.x < BIN_NODES) {
    int node = nodeBase + threadIdx.x;
    if (node < N) {
      int c = cnt[threadIdx.x];
      count[node] = c;
      dis[node] = rsqrtf((float)(c + 1));  // +1 self loop
    }
  }
}

// --- hierarchical exclusive scan over count[0..N) -> rowptr ------------------
__global__ void scan_partial(const int* __restrict__ count, int* __restrict__ bsum, int N) {
  __shared__ int s[256];
  int t = threadIdx.x, b = blockIdx.x;
  int base = b * 1024 + t * 4;
  int sum = 0;
#pragma unroll
  for (int i = 0; i < 4; i++) sum += (base + i < N) ? count[base + i] : 0;
  s[t] = sum;
  __syncthreads();
  for (int d = 128; d > 0; d >>= 1) {
    if (t < d) s[t] += s[t + d];
    __syncthreads();
  }
  if (t == 0) bsum[b] = s[0];
}

__global__ void scan_blocksums(int* __restrict__ bsum, int nb) {
  __shared__ int s[256];
  int t = threadIdx.x;
  int v = (t < nb) ? bsum[t] : 0;
  s[t] = v;
  __syncthreads();
  for (int d = 1; d < 256; d <<= 1) {
    int add = (t >= d) ? s[t - d] : 0;
    __syncthreads();
    s[t] += add;
    __syncthreads();
  }
  if (t < nb) bsum[t] = s[t] - v;  // exclusive
}

__global__ void scan_final(const int* __restrict__ count, const int* __restrict__ bsum,
                           int* __restrict__ rowptr, int N, int E) {
  __shared__ int s[256];
  int t = threadIdx.x, b = blockIdx.x;
  int base = b * 1024 + t * 4;
  int c[4];
  int sum = 0;
#pragma unroll
  for (int i = 0; i < 4; i++) {
    c[i] = (base + i < N) ? count[base + i] : 0;
    sum += c[i];
  }
  int v = sum;
  s[t] = v;
  __syncthreads();
  for (int d = 1; d < 256; d <<= 1) {
    int add = (t >= d) ? s[t - d] : 0;
    __syncthreads();
    s[t] += add;
    __syncthreads();
  }
  int run = bsum[b] + (s[t] - v);
#pragma unroll
  for (int i = 0; i < 4; i++) {
    if (base + i < N) {
      rowptr[base + i] = run;
      run += c[i];
    }
  }
  if (b == 0 && t == 0) rowptr[N] = E;
}

// --- pass D: per-bin CSR fill (writes confined to ~16 KB window) ------------
__global__ __launch_bounds__(256) void csr_fill(const int2* __restrict__ binbuf,
                                                const int* __restrict__ binStart,
                                                const int* __restrict__ rowptr,
                                                const float* __restrict__ dis, int N,
                                                int* __restrict__ col, float* __restrict__ wgt) {
  __shared__ int cur[BIN_NODES];
  __shared__ float dloc[BIN_NODES];
  int b = blockIdx.x;
  int nodeBase = b << BIN_SHIFT;
  if (threadIdx.x < BIN_NODES) {
    int node = nodeBase + threadIdx.x;
    cur[threadIdx.x] = (node < N) ? rowptr[node] : 0;
    dloc[threadIdx.x] = (node < N) ? dis[node] : 0.f;
  }
  __syncthreads();
  int s0 = binStart[b], s1 = binStart[b + 1];
  for (int i = s0 + threadIdx.x; i < s1; i += 256) {
    int2 e = binbuf[i];
    int dl = e.y - nodeBase;
    int slot = atomicAdd(&cur[dl], 1);
    col[slot] = e.x;
    wgt[slot] = dis[e.x] * dloc[dl];
  }
}

// --- GEMM: C[M][64] = A[M][K] @ W[K][64], W staged in LDS -------------------
template <int K>
__global__ __launch_bounds__(256) void gemm64(const float* __restrict__ A,
                                              const float* __restrict__ W,
                                              float* __restrict__ C, int M) {
  __shared__ float4 wlds[K * 16];  // K rows x 16 float4 (64 cols)
  {
    const float4* W4 = (const float4*)W;
    for (int i = threadIdx.x; i < K * 16; i += 256) wlds[i] = W4[i];
  }
  __syncthreads();

  const int c0 = threadIdx.x & 15;   // which float4 of the 64-col row
  const int rq = threadIdx.x >> 4;   // row quad within block
  const int r0 = blockIdx.x * 64 + rq * 4;
  if (r0 >= M) return;

  float4 acc[4];
#pragma unroll
  for (int i = 0; i < 4; i++) acc[i] = make_float4(0.f, 0.f, 0.f, 0.f);
  size_t aoff[4];
  bool ok[4];
#pragma unroll
  for (int i = 0; i < 4; i++) {
    int r = r0 + i;
    ok[i] = (r < M);
    aoff[i] = (size_t)(ok[i] ? r : (M - 1)) * K;  // clamp: no OOB, result discarded
  }

#pragma unroll 2
  for (int k = 0; k < K; k += 4) {
    float4 xv[4];
#pragma unroll
    for (int i = 0; i < 4; i++) xv[i] = *(const float4*)(A + aoff[i] + k);
    float4 w0 = wlds[(k + 0) * 16 + c0];
    float4 w1 = wlds[(k + 1) * 16 + c0];
    float4 w2 = wlds[(k + 2) * 16 + c0];
    float4 w3 = wlds[(k + 3) * 16 + c0];
#pragma unroll
    for (int i = 0; i < 4; i++) {
      acc[i].x += xv[i].x * w0.x + xv[i].y * w1.x + xv[i].z * w2.x + xv[i].w * w3.x;
      acc[i].y += xv[i].x * w0.y + xv[i].y * w1.y + xv[i].z * w2.y + xv[i].w * w3.y;
      acc[i].z += xv[i].x * w0.z + xv[i].y * w1.z + xv[i].z * w2.z + xv[i].w * w3.z;
      acc[i].w += xv[i].x * w0.w + xv[i].y * w1.w + xv[i].z * w2.w + xv[i].w * w3.w;
    }
  }
#pragma unroll
  for (int i = 0; i < 4; i++)
    if (ok[i]) *(float4*)&C[(size_t)(r0 + i) * 64 + c0 * 4] = acc[i];
}

// --- aggregation: wave per node, TWO edges per wave in flight ---------------
__global__ __launch_bounds__(256) void agg_kernel(
    const float2* __restrict__ h, const int* __restrict__ rowptr, const int* __restrict__ col,
    const float* __restrict__ wgt, const float* __restrict__ dis, const float* __restrict__ bias,
    float2* __restrict__ out, int N, int relu) {
  int wid = (blockIdx.x * blockDim.x + threadIdx.x) >> 6;
  if (wid >= N) return;
  int lane = threadIdx.x & 63;
  int sub = lane & 31;    // float2 index within the 64-float row
  int half = lane >> 5;   // which edge of the pair

  int start = rowptr[wid], end = rowptr[wid + 1];
  float di = dis[wid];

  float2 a0 = make_float2(0.f, 0.f), a1 = a0, a2 = a0, a3 = a0;
  {  // self-loop term (half 0 only; halves are summed at the end)
    float2 self = h[(size_t)wid * 32 + sub];
    if (half == 0) {
      a0.x = di * di * self.x;
      a0.y = di * di * self.y;
    }
  }

  for (int base = start; base < end; base += 64) {
    int e = base + lane;
    int sj = 0;
    float wj = 0.f;
    if (e < end) {
      sj = col[e];
      wj = wgt[e];
    }
    int cnt = end - base;
    if (cnt > 64) cnt = 64;
    int rounds = (cnt + 1) >> 1;  // edge pairs in this chunk
    int t = 0;
    for (; t + 4 <= rounds; t += 4) {
      int i0 = 2 * t + half;
      int s0 = __shfl(sj, i0), s1 = __shfl(sj, i0 + 2), s2 = __shfl(sj, i0 + 4),
          s3 = __shfl(sj, i0 + 6);
      float w0 = __shfl(wj, i0), w1 = __shfl(wj, i0 + 2), w2 = __shfl(wj, i0 + 4),
            w3 = __shfl(wj, i0 + 6);
      float2 g0 = h[(size_t)s0 * 32 + sub];
      float2 g1 = h[(size_t)s1 * 32 + sub];
      float2 g2 = h[(size_t)s2 * 32 + sub];
      float2 g3 = h[(size_t)s3 * 32 + sub];
      a0.x += w0 * g0.x; a0.y += w0 * g0.y;
      a1.x += w1 * g1.x; a1.y += w1 * g1.y;
      a2.x += w2 * g2.x; a2.y += w2 * g2.y;
      a3.x += w3 * g3.x; a3.y += w3 * g3.y;
    }
    for (; t < rounds; t++) {
      int i0 = 2 * t + half;  // may point one past cnt for odd cnt: wj there is 0
      int s0 = __shfl(sj, i0);
      float w0 = __shfl(wj, i0);
      float2 g0 = h[(size_t)s0 * 32 + sub];
      a0.x += w0 * g0.x; a0.y += w0 * g0.y;
    }
  }

  float sx = (a0.x + a1.x) + (a2.x + a3.x);
  float sy = (a0.y + a1.y) + (a2.y + a3.y);
  sx += __shfl_down(sx, 32);  // fold half 1 into half 0
  sy += __shfl_down(sy, 32);
  if (half == 0) {
    float2 bv = ((const float2*)bias)[sub];
    float ox = sx + bv.x, oy = sy + bv.y;
    if (relu) {
      ox = fmaxf(ox, 0.f);
      oy = fmaxf(oy, 0.f);
    }
    out[(size_t)wid * 32 + sub] = make_float2(ox, oy);
  }
}

// ---------------------------------------------------------------------------
extern "C" void kernel_launch(void* const* d_in, const int* in_sizes, int n_in,
                              void* d_out, int out_size, void* d_ws, size_t ws_size,
                              hipStream_t stream) {
  const float* x = (const float*)d_in[0];
  const int* ei = (const int*)d_in[1];
  const float* W1 = (const float*)d_in[2];
  const float* b1 = (const float*)d_in[3];
  const float* W2 = (const float*)d_in[4];
  const float* b2 = (const float*)d_in[5];

  const int IN = 256;
  const int E = in_sizes[1] / 2;
  const int N = in_sizes[0] / IN;
  const int* src = ei;      // edge_index[0]
  const int* dst = ei + E;  // edge_index[1]
  const int nbins = (N + BIN_NODES - 1) >> BIN_SHIFT;

  // workspace carve-up (256B aligned)
  char* ws = (char*)d_ws;
  size_t off = 0;
  auto alloc = [&](size_t bytes) -> void* {
    void* p = ws + off;
    off += (bytes + 255) & ~(size_t)255;
    return p;
  };
  int* count = (int*)alloc((size_t)N * 4);
  int* rowptr = (int*)alloc((size_t)(N + 1) * 4);
  float* dis = (float*)alloc((size_t)N * 4);
  int* bsum = (int*)alloc(4096);
  int* binCnt = (int*)alloc(MAX_BINS * 4);
  int* binStart = (int*)alloc((MAX_BINS + 1) * 4);
  int* binCursor = (int*)alloc(MAX_BINS * 4);
  int* col = (int*)alloc((size_t)E * 4);
  float* wgt = (float*)alloc((size_t)E * 4);
  // binbuf (E int2) aliases h (N*64 fp32): binbuf dead once csr_fill is done,
  // h first written by gemm1 afterwards.  25.6 MB each.
  size_t big = ((size_t)E * 8 > (size_t)N * 256) ? (size_t)E * 8 : (size_t)N * 256;
  int2* binbuf = (int2*)alloc(big);
  float* h = (float*)binbuf;
  float* out1 = (float*)d_out;  // layer-1 output staged in d_out
  float* outf = (float*)d_out;

  const int tb = 256;
  const int nb = (N + 1023) / 1024;

  zero_int<<<(nbins + tb - 1) / tb, tb, 0, stream>>>(binCnt, nbins);
  bin_count<<<256, 256, 0, stream>>>(dst, E, nbins, binCnt);
  bin_scan<<<1, 256, 0, stream>>>(binCnt, nbins, E, binStart, binCursor);
  bin_fill<<<256, 256, 0, stream>>>(src, dst, E, nbins, binCursor, binbuf);
  node_count_dis<<<nbins, 256, 0, stream>>>(binbuf, binStart, N, count, dis);
  scan_partial<<<nb, 256, 0, stream>>>(count, bsum, N);
  scan_blocksums<<<1, 256, 0, stream>>>(bsum, nb);
  scan_final<<<nb, 256, 0, stream>>>(count, bsum, rowptr, N, E);
  csr_fill<<<nbins, 256, 0, stream>>>(binbuf, binStart, rowptr, dis, N, col, wgt);

  gemm64<256><<<(N + 63) / 64, 256, 0, stream>>>(x, W1, h, N);
  agg_kernel<<<(N + 3) / 4, 256, 0, stream>>>((const float2*)h, rowptr, col, wgt, dis, b1,
                                              (float2*)out1, N, 1);
  gemm64<64><<<(N + 63) / 64, 256, 0, stream>>>(out1, W2, h, N);
  agg_kernel<<<(N + 3) / 4, 256, 0, stream>>>((const float2*)h, rowptr, col, wgt, dis, b2,
                                              (float2*)outf, N, 0);
}